// Round 4
// baseline (672.729 us; speedup 1.0000x reference)
//
#include <hip/hip_runtime.h>
#include <hip/hip_bf16.h>

#define Hh   64      // LSTM hidden
#define G4   256     // 4*H gate width
#define Dd   128     // input feature dim
#define Bsz  256     // batch
#define Tt   1024    // time steps
#define NOUT 10      // dense classes

typedef __bf16  bf16x8 __attribute__((ext_vector_type(8)));
typedef float   f32x4v __attribute__((ext_vector_type(4)));

// ---------------------------------------------------------------------------
// K0: Wt[n][k] = bf16(W[k][n])  (transpose + convert, trivial)
// ---------------------------------------------------------------------------
__global__ __launch_bounds__(128)
void k0_wt(const float* __restrict__ W, __bf16* __restrict__ Wt) {
    const int n = blockIdx.x;    // 0..255 (gate col)
    const int k = threadIdx.x;   // 0..127 (input dim)
    Wt[(size_t)n * Dd + k] = (__bf16)W[(size_t)k * G4 + n];
}

// ---------------------------------------------------------------------------
// K1: xw = x @ W + b via mfma_f32_16x16x32_bf16, natural [row][col] bf16 store.
// Block = 4 waves = 128 rows x 256 cols.
// ---------------------------------------------------------------------------
#define K1_RT 8   // 16-row tiles per block -> 128 rows/block

__global__ __launch_bounds__(256)
void k1_mfma(const float* __restrict__ x, const __bf16* __restrict__ Wt,
             const float* __restrict__ bias, __bf16* __restrict__ xw) {
    const int tid = threadIdx.x;
    const int w   = tid >> 6;      // wave 0..3
    const int l   = tid & 63;
    const int r16 = l & 15;
    const int kq  = l >> 4;        // 0..3
    const size_t rowbase = (size_t)blockIdx.x * (16 * K1_RT);

    bf16x8 bfr[4][4];
    float  bval[4];
#pragma unroll
    for (int ct = 0; ct < 4; ++ct) {
        const int col = w * 64 + ct * 16 + r16;
        const __bf16* wp = Wt + (size_t)col * Dd + kq * 8;
#pragma unroll
        for (int kk = 0; kk < 4; ++kk)
            bfr[ct][kk] = *(const bf16x8*)(wp + kk * 32);
        bval[ct] = bias[col];
    }

    for (int rt = 0; rt < K1_RT; ++rt) {
        const size_t arow = rowbase + rt * 16 + r16;
        const float* xr = x + arow * Dd + kq * 8;
        bf16x8 afr[4];
#pragma unroll
        for (int kk = 0; kk < 4; ++kk) {
            const float4 lo = *(const float4*)(xr + kk * 32);
            const float4 hi = *(const float4*)(xr + kk * 32 + 4);
            afr[kk][0] = (__bf16)lo.x; afr[kk][1] = (__bf16)lo.y;
            afr[kk][2] = (__bf16)lo.z; afr[kk][3] = (__bf16)lo.w;
            afr[kk][4] = (__bf16)hi.x; afr[kk][5] = (__bf16)hi.y;
            afr[kk][6] = (__bf16)hi.z; afr[kk][7] = (__bf16)hi.w;
        }
        f32x4v acc[4];
#pragma unroll
        for (int ct = 0; ct < 4; ++ct)
            acc[ct] = (f32x4v){bval[ct], bval[ct], bval[ct], bval[ct]};
#pragma unroll
        for (int ct = 0; ct < 4; ++ct)
#pragma unroll
            for (int kk = 0; kk < 4; ++kk)
                acc[ct] = __builtin_amdgcn_mfma_f32_16x16x32_bf16(
                              afr[kk], bfr[ct][kk], acc[ct], 0, 0, 0);

        const size_t orow0 = rowbase + rt * 16 + kq * 4;
#pragma unroll
        for (int ct = 0; ct < 4; ++ct) {
            const int col = w * 64 + ct * 16 + r16;
#pragma unroll
            for (int rr = 0; rr < 4; ++rr)
                xw[(orow0 + rr) * G4 + col] = (__bf16)acc[ct][rr];
        }
    }
}

// ---------------------------------------------------------------------------
// K2: LSTM scan. 2 batch rows per block (512 thr, 8 waves) -> 2 waves/SIMD
// so the two rows' waves hide each other's latency.
// Thread (r,g): z[g] via 64 fp32 FMAs from its OWN WAVE's private hs copy
// (broadcast reads, no cross-wave dependency). z exchanged via
// double-buffered zs + ONE barrier. All waves then redundantly compute
// gates for h-index l=g&63 (identical fp32 math -> identical results) and
// write their private hs copy (wave-internal, no barrier).
// ---------------------------------------------------------------------------
#define RPB 2   // rows per block

__global__ __launch_bounds__(512)
void k2_scan(const __bf16* __restrict__ xw, const float* __restrict__ U,
             float* __restrict__ hout) {
    const int tid = threadIdx.x;
    const int r   = tid >> 8;          // row within block (0..1)
    const int g   = tid & 255;         // gate column
    const int w4  = g >> 6;            // wave within row (0..3)
    const int l   = g & 63;            // h index owned for gate phase
    const int brow = blockIdx.x * RPB + r;

    __shared__ float zs[2][RPB][G4];                    // double-buffered z
    __shared__ __align__(16) float hs[2][RPB][4][Hh];   // wave-private h copies

    float u[Hh];
#pragma unroll
    for (int j = 0; j < Hh; ++j) u[j] = U[(size_t)j * G4 + g];

    float c = 0.f;
    hs[0][r][w4][l] = 0.f;

    const __bf16* __restrict__ xwp = xw + (size_t)brow * Tt * G4 + g;
    float zcur = (float)xwp[0];
    float znx  = (float)xwp[G4];
    __syncthreads();

    for (int t = 0; t < Tt; ++t) {
        const int p  = t & 1;
        const int t2 = (t + 2 < Tt) ? (t + 2) : (Tt - 1);
        const float zpp = (float)xwp[(size_t)t2 * G4];   // prefetch depth 2

        // z[g] = xw + h . U[:,g]  from own wave's hs copy (broadcast reads)
        const float* __restrict__ hp = hs[p][r][w4];
        float a0 = zcur, a1 = 0.f, a2 = 0.f, a3 = 0.f;
#pragma unroll
        for (int j = 0; j < Hh; j += 4) {
            const f32x4v h4 = *(const f32x4v*)&hp[j];
            a0 = fmaf(h4[0], u[j + 0], a0);
            a1 = fmaf(h4[1], u[j + 1], a1);
            a2 = fmaf(h4[2], u[j + 2], a2);
            a3 = fmaf(h4[3], u[j + 3], a3);
        }
        zs[p][r][g] = (a0 + a1) + (a2 + a3);
        __syncthreads();

        // every wave: gates for h-index l (redundant x4, deterministic)
        const float zi = zs[p][r][l];
        const float zf = zs[p][r][64 + l];
        const float zg = zs[p][r][128 + l];
        const float zo = zs[p][r][192 + l];
        const float gi = fminf(fmaxf(0.2f * zi + 0.5f, 0.f), 1.f);
        const float gf = fminf(fmaxf(0.2f * zf + 0.5f, 0.f), 1.f);
        const float gg = fmaxf(zg, 0.f);
        const float go = fminf(fmaxf(0.2f * zo + 0.5f, 0.f), 1.f);
        c = gf * c + gi * gg;
        const float h = go * fmaxf(c, 0.f);

        hs[1 - p][r][w4][l] = h;    // own wave's copy: no barrier needed
        zcur = znx; znx = zpp;
    }
    // Tt even -> final h in buffer 0; wave 0 of each row wrote it itself
    if (w4 == 0) hout[(size_t)brow * Hh + l] = hs[0][r][0][l];
}

// ---------------------------------------------------------------------------
// K3: out[r,:] = softmax(h[r,:] @ Wd + bd). One block, thread = batch row.
// ---------------------------------------------------------------------------
__global__ __launch_bounds__(256)
void k3_dense(const float* __restrict__ hin, const float* __restrict__ Wd,
              const float* __restrict__ bd, float* __restrict__ out) {
    __shared__ float wd[Hh * NOUT];
    __shared__ float bds[NOUT];
    for (int i = threadIdx.x; i < Hh * NOUT; i += blockDim.x) wd[i] = Wd[i];
    if (threadIdx.x < NOUT) bds[threadIdx.x] = bd[threadIdx.x];
    __syncthreads();

    const int r = threadIdx.x;
    if (r < Bsz) {
        float hrow[Hh];
#pragma unroll
        for (int j = 0; j < Hh; ++j) hrow[j] = hin[(size_t)r * Hh + j];
        float logits[NOUT];
#pragma unroll
        for (int o = 0; o < NOUT; ++o) {
            float acc = bds[o];
#pragma unroll
            for (int j = 0; j < Hh; ++j) acc = fmaf(hrow[j], wd[j * NOUT + o], acc);
            logits[o] = acc;
        }
        float mx = logits[0];
#pragma unroll
        for (int o = 1; o < NOUT; ++o) mx = fmaxf(mx, logits[o]);
        float s = 0.f;
#pragma unroll
        for (int o = 0; o < NOUT; ++o) { logits[o] = expf(logits[o] - mx); s += logits[o]; }
        const float inv = 1.f / s;
#pragma unroll
        for (int o = 0; o < NOUT; ++o) out[(size_t)r * NOUT + o] = logits[o] * inv;
    }
}

// ---------------------------------------------------------------------------
extern "C" void kernel_launch(void* const* d_in, const int* in_sizes, int n_in,
                              void* d_out, int out_size, void* d_ws, size_t ws_size,
                              hipStream_t stream) {
    const float* x  = (const float*)d_in[0];
    const float* W  = (const float*)d_in[1];
    const float* U  = (const float*)d_in[2];
    const float* b  = (const float*)d_in[3];
    const float* Wd = (const float*)d_in[4];
    const float* bd = (const float*)d_in[5];
    float* out = (float*)d_out;

    const size_t xw_bytes = (size_t)Bsz * Tt * G4 * sizeof(__bf16);   // 128 MiB
    __bf16* xw   = (__bf16*)d_ws;
    float*  hbuf = (float*)((char*)d_ws + xw_bytes);
    __bf16* Wt   = (__bf16*)((char*)d_ws + xw_bytes + (size_t)Bsz * Hh * sizeof(float));

    k0_wt<<<G4, Dd, 0, stream>>>(W, Wt);
    k1_mfma<<<(Bsz * Tt) / (16 * K1_RT), 256, 0, stream>>>(x, Wt, b, xw);
    k2_scan<<<Bsz / RPB, 512, 0, stream>>>(xw, U, hbuf);
    k3_dense<<<1, 256, 0, stream>>>(hbuf, Wd, bd, out);
}

// Round 5
// 570.771 us; speedup vs baseline: 1.1786x; 1.1786x over previous
//
#include <hip/hip_runtime.h>
#include <hip/hip_bf16.h>

#define Hh   64      // LSTM hidden
#define G4   256     // 4*H gate width
#define Dd   128     // input feature dim
#define Bsz  256     // batch
#define Tt   1024    // time steps
#define NOUT 10      // dense classes

typedef __bf16  bf16x8 __attribute__((ext_vector_type(8)));
typedef __bf16  bf16x4 __attribute__((ext_vector_type(4)));
typedef float   f32x4v __attribute__((ext_vector_type(4)));

// ---------------------------------------------------------------------------
// K0: Wt[n][k] = bf16(W[k][n])  (transpose + convert, trivial)
// ---------------------------------------------------------------------------
__global__ __launch_bounds__(128)
void k0_wt(const float* __restrict__ W, __bf16* __restrict__ Wt) {
    const int n = blockIdx.x;    // 0..255 (gate col)
    const int k = threadIdx.x;   // 0..127 (input dim)
    Wt[(size_t)n * Dd + k] = (__bf16)W[(size_t)k * G4 + n];
}

// ---------------------------------------------------------------------------
// K1: xw = x @ W + b via mfma_f32_16x16x32_bf16, natural [row][col] bf16 store.
// Block = 4 waves = 128 rows x 256 cols. (unchanged, ~65us)
// ---------------------------------------------------------------------------
#define K1_RT 8   // 16-row tiles per block -> 128 rows/block

__global__ __launch_bounds__(256)
void k1_mfma(const float* __restrict__ x, const __bf16* __restrict__ Wt,
             const float* __restrict__ bias, __bf16* __restrict__ xw) {
    const int tid = threadIdx.x;
    const int w   = tid >> 6;      // wave 0..3
    const int l   = tid & 63;
    const int r16 = l & 15;
    const int kq  = l >> 4;        // 0..3
    const size_t rowbase = (size_t)blockIdx.x * (16 * K1_RT);

    bf16x8 bfr[4][4];
    float  bval[4];
#pragma unroll
    for (int ct = 0; ct < 4; ++ct) {
        const int col = w * 64 + ct * 16 + r16;
        const __bf16* wp = Wt + (size_t)col * Dd + kq * 8;
#pragma unroll
        for (int kk = 0; kk < 4; ++kk)
            bfr[ct][kk] = *(const bf16x8*)(wp + kk * 32);
        bval[ct] = bias[col];
    }

    for (int rt = 0; rt < K1_RT; ++rt) {
        const size_t arow = rowbase + rt * 16 + r16;
        const float* xr = x + arow * Dd + kq * 8;
        bf16x8 afr[4];
#pragma unroll
        for (int kk = 0; kk < 4; ++kk) {
            const float4 lo = *(const float4*)(xr + kk * 32);
            const float4 hi = *(const float4*)(xr + kk * 32 + 4);
            afr[kk][0] = (__bf16)lo.x; afr[kk][1] = (__bf16)lo.y;
            afr[kk][2] = (__bf16)lo.z; afr[kk][3] = (__bf16)lo.w;
            afr[kk][4] = (__bf16)hi.x; afr[kk][5] = (__bf16)hi.y;
            afr[kk][6] = (__bf16)hi.z; afr[kk][7] = (__bf16)hi.w;
        }
        f32x4v acc[4];
#pragma unroll
        for (int ct = 0; ct < 4; ++ct)
            acc[ct] = (f32x4v){bval[ct], bval[ct], bval[ct], bval[ct]};
#pragma unroll
        for (int ct = 0; ct < 4; ++ct)
#pragma unroll
            for (int kk = 0; kk < 4; ++kk)
                acc[ct] = __builtin_amdgcn_mfma_f32_16x16x32_bf16(
                              afr[kk], bfr[ct][kk], acc[ct], 0, 0, 0);

        const size_t orow0 = rowbase + rt * 16 + kq * 4;
#pragma unroll
        for (int ct = 0; ct < 4; ++ct) {
            const int col = w * 64 + ct * 16 + r16;
#pragma unroll
            for (int rr = 0; rr < 4; ++rr)
                xw[(orow0 + rr) * G4 + col] = (__bf16)acc[ct][rr];
        }
    }
}

// ---------------------------------------------------------------------------
// K2: LSTM scan via MFMA. 16 batch rows per block, 4 waves, 16 blocks.
// z^T[gate][batch] = Ut . h^T + xw^T  with mfma_f32_16x16x32_bf16:
//   A = Ut frags (const, regs), B = h^T (LDS, XOR-swizzled), C = xw (global
//   prefetch depth 4, fully unrolled -> static reg indexing).
// Wave w owns gate tiles {w,w+4,w+8,w+12} -> lane 16q+m holds all 4 gates of
// h-idx 16w+4q+r for batch m in ITS OWN accs: gate math is register-only.
// One raw s_barrier per step (manual lgkmcnt; vmcnt NOT drained so the
// global prefetch stays in flight across barriers).
// ---------------------------------------------------------------------------
__global__ __launch_bounds__(256)
void k2_scan(const __bf16* __restrict__ xw, const float* __restrict__ U,
             float* __restrict__ hout) {
    const int tid = threadIdx.x;
    const int w   = tid >> 6;      // wave 0..3
    const int l   = tid & 63;
    const int q   = l >> 4;        // 0..3
    const int m   = l & 15;        // batch-in-group / gate-in-tile
    const int b0  = blockIdx.x * 16;

    // h^T staging: [parity][batch m][128 bytes = 64 bf16], XOR-swizzled:
    // 16B slot index ^= (m & 7).
    __shared__ __align__(16) unsigned char hlds[2][16 * 128];

    // A-frags: Ut for tiles gt = w + 4*tt, ksteps s: A[row m][k=q*8+j+32s]
    bf16x8 au[4][2];
#pragma unroll
    for (int tt = 0; tt < 4; ++tt)
#pragma unroll
        for (int s = 0; s < 2; ++s)
#pragma unroll
            for (int j = 0; j < 8; ++j)
                au[tt][s][j] = (__bf16)U[(size_t)(q * 8 + j + 32 * s) * G4
                                         + 16 * (w + 4 * tt) + m];

    // per-lane global base for xw reads: row (b0+m), col 16w + 64tt + 4q
    const unsigned char* lanebase = (const unsigned char*)xw
        + (size_t)(b0 + m) * Tt * (G4 * 2) + (size_t)(16 * w + 4 * q) * 2;

    // prime prefetch: steps 0..3 into sets 0..3
    uint2 xzp[4][4];
#pragma unroll
    for (int s4 = 0; s4 < 4; ++s4)
#pragma unroll
        for (int tt = 0; tt < 4; ++tt)
            xzp[s4][tt] = *(const uint2*)(lanebase + (size_t)s4 * 512 + tt * 128);

    bf16x8 bh0{}, bh1{};           // h^T frags (h_0 = 0)
    float  c[4]  = {0.f, 0.f, 0.f, 0.f};
    float  hcur[4] = {0.f, 0.f, 0.f, 0.f};

    const int wslot = ((2 * w + (q >> 1)) ^ (m & 7));     // write slot
    const int wbyte = m * 128 + (wslot << 4) + ((q & 1) << 3);
    const int rbyte0 = m * 128 + (((q + 0) ^ (m & 7)) << 4);
    const int rbyte1 = m * 128 + (((q + 4) ^ (m & 7)) << 4);

    for (int t0 = 0; t0 < Tt; t0 += 4) {
#pragma unroll
        for (int s4 = 0; s4 < 4; ++s4) {
            const int t = t0 + s4;
            const int p = t & 1;

            // ---- C init from prefetched xw (bf16 pair -> f32 via shifts)
            f32x4v acc[4];
#pragma unroll
            for (int tt = 0; tt < 4; ++tt) {
                const uint2 pr = xzp[s4][tt];
                acc[tt][0] = __builtin_bit_cast(float, pr.x << 16);
                acc[tt][1] = __builtin_bit_cast(float, pr.x & 0xFFFF0000u);
                acc[tt][2] = __builtin_bit_cast(float, pr.y << 16);
                acc[tt][3] = __builtin_bit_cast(float, pr.y & 0xFFFF0000u);
            }

            // ---- issue prefetch for t+4 into the set just consumed
            {
                int tp = t + 4; if (tp > Tt - 1) tp = Tt - 1;
                const unsigned char* pb = lanebase + (size_t)tp * 512;
#pragma unroll
                for (int tt = 0; tt < 4; ++tt)
                    xzp[s4][tt] = *(const uint2*)(pb + tt * 128);
            }

            // ---- z^T = Ut . h^T + xw   (8 MFMA)
#pragma unroll
            for (int tt = 0; tt < 4; ++tt) {
                acc[tt] = __builtin_amdgcn_mfma_f32_16x16x32_bf16(
                              au[tt][0], bh0, acc[tt], 0, 0, 0);
                acc[tt] = __builtin_amdgcn_mfma_f32_16x16x32_bf16(
                              au[tt][1], bh1, acc[tt], 0, 0, 0);
            }

            // ---- gates (register-only): lane has zi,zf,zg,zo for
            //      h-idx 16w+4q+r, batch m
            bf16x4 hv;
#pragma unroll
            for (int r = 0; r < 4; ++r) {
                const float zi = acc[0][r], zf = acc[1][r];
                const float zg = acc[2][r], zo = acc[3][r];
                const float gi = fminf(fmaxf(fmaf(0.2f, zi, 0.5f), 0.f), 1.f);
                const float gf = fminf(fmaxf(fmaf(0.2f, zf, 0.5f), 0.f), 1.f);
                const float gg = fmaxf(zg, 0.f);
                const float go = fminf(fmaxf(fmaf(0.2f, zo, 0.5f), 0.f), 1.f);
                c[r] = fmaf(gf, c[r], gi * gg);
                const float h = go * fmaxf(c[r], 0.f);
                hcur[r] = h;
                hv[r] = (__bf16)h;
            }

            // ---- h(t+1) -> LDS (swizzled b64), barrier WITHOUT vmcnt drain
            *(bf16x4*)&hlds[p ^ 1][wbyte] = hv;
            asm volatile("s_waitcnt lgkmcnt(0)" ::: "memory");
            __builtin_amdgcn_sched_barrier(0);
            __builtin_amdgcn_s_barrier();
            __builtin_amdgcn_sched_barrier(0);

            // ---- B-frags for next step: h^T[k][batch m]
            bh0 = *(const bf16x8*)&hlds[p ^ 1][rbyte0];
            bh1 = *(const bf16x8*)&hlds[p ^ 1][rbyte1];
        }
    }

    // final h (f32, from last gate phase): batch m, h-idx 16w+4q .. +3
    *(float4*)&hout[(size_t)(b0 + m) * Hh + 16 * w + 4 * q] =
        (float4){hcur[0], hcur[1], hcur[2], hcur[3]};
}

// ---------------------------------------------------------------------------
// K3: out[r,:] = softmax(h[r,:] @ Wd + bd). One block, thread = batch row.
// ---------------------------------------------------------------------------
__global__ __launch_bounds__(256)
void k3_dense(const float* __restrict__ hin, const float* __restrict__ Wd,
              const float* __restrict__ bd, float* __restrict__ out) {
    __shared__ float wd[Hh * NOUT];
    __shared__ float bds[NOUT];
    for (int i = threadIdx.x; i < Hh * NOUT; i += blockDim.x) wd[i] = Wd[i];
    if (threadIdx.x < NOUT) bds[threadIdx.x] = bd[threadIdx.x];
    __syncthreads();

    const int r = threadIdx.x;
    if (r < Bsz) {
        float hrow[Hh];
#pragma unroll
        for (int j = 0; j < Hh; ++j) hrow[j] = hin[(size_t)r * Hh + j];
        float logits[NOUT];
#pragma unroll
        for (int o = 0; o < NOUT; ++o) {
            float acc = bds[o];
#pragma unroll
            for (int j = 0; j < Hh; ++j) acc = fmaf(hrow[j], wd[j * NOUT + o], acc);
            logits[o] = acc;
        }
        float mx = logits[0];
#pragma unroll
        for (int o = 1; o < NOUT; ++o) mx = fmaxf(mx, logits[o]);
        float s = 0.f;
#pragma unroll
        for (int o = 0; o < NOUT; ++o) { logits[o] = expf(logits[o] - mx); s += logits[o]; }
        const float inv = 1.f / s;
#pragma unroll
        for (int o = 0; o < NOUT; ++o) out[(size_t)r * NOUT + o] = logits[o] * inv;
    }
}

// ---------------------------------------------------------------------------
extern "C" void kernel_launch(void* const* d_in, const int* in_sizes, int n_in,
                              void* d_out, int out_size, void* d_ws, size_t ws_size,
                              hipStream_t stream) {
    const float* x  = (const float*)d_in[0];
    const float* W  = (const float*)d_in[1];
    const float* U  = (const float*)d_in[2];
    const float* b  = (const float*)d_in[3];
    const float* Wd = (const float*)d_in[4];
    const float* bd = (const float*)d_in[5];
    float* out = (float*)d_out;

    const size_t xw_bytes = (size_t)Bsz * Tt * G4 * sizeof(__bf16);   // 128 MiB
    __bf16* xw   = (__bf16*)d_ws;
    float*  hbuf = (float*)((char*)d_ws + xw_bytes);
    __bf16* Wt   = (__bf16*)((char*)d_ws + xw_bytes + (size_t)Bsz * Hh * sizeof(float));

    k0_wt<<<G4, Dd, 0, stream>>>(W, Wt);
    k1_mfma<<<(Bsz * Tt) / (16 * K1_RT), 256, 0, stream>>>(x, Wt, b, xw);
    k2_scan<<<Bsz / 16, 256, 0, stream>>>(xw, U, hbuf);
    k3_dense<<<1, 256, 0, stream>>>(hbuf, Wd, bd, out);
}